// Round 1
// baseline (993.662 us; speedup 1.0000x reference)
//
#include <hip/hip_runtime.h>

// Fused windowed multi-head attention for MI355X (gfx950).
// B=8192 windows, N=49 tokens, C=192, H=6 heads, HD=32.
// Inputs/outputs are FP32 (per reference); mask int32. Interior compute bf16 MFMA.
//
// Structure: 1 block per window, 6 waves (one per head).
//   phase 1: stage x fp32 -> bf16 (49x192 -> 64x200 padded) + mask bias in LDS
//   phase 2: QKV GEMM  (per wave: 96 cols = q|k|v of its head), mfma 16x16x32 bf16
//   phase 3: q,k row-major + v^T to per-head LDS buffers (XOR-swizzled, no pad)
//   phase 4: S = Q K^T (single K-step), masked softmax in registers (shfl_xor)
//   phase 5: O = P V   (P round-trips LDS in A-layout, v^T as B operand)
//   phase 6: O tile (64x192) to LDS, cooperative projection GEMM + bias, fp32 store
//
// v2 (occupancy): per-head LDS cut 7424 -> 6144 shorts by replacing pad-stride
// buffers (q/k stride 40, vt/p stride 72) with XOR-swizzled natural strides:
//   q[64][32], k[64][32]  : idx = row*32 + (((col>>3) ^ (row&3))<<3 | (col&7))
//   vt[32][64], p[64][64] : idx = row*64 + (((col>>3) ^ (row&7))<<3 | (col&7))
// Swizzled ds_read_b128 patterns land exactly 8 lanes per 16B bank column
// (the b128 minimum). Region: 44544 -> 36864 shorts (89.3 KB -> 74.0 KB LDS)
// => 2 blocks/CU (12 waves/CU) instead of 1 (6 waves/CU).
// __launch_bounds__(384,3) pins the 3-waves/SIMD target (VGPR cap 168; uses 128).
//
// Weights are repacked each call (d_ws re-poisoned) fp32 -> bf16 in
// B-fragment-contiguous layout: wp[(kt*COLS + col)*32 + kk] = w[(kt*32+kk)*COLS + col]
// so each MFMA B-fragment is one 16B load (full wave reads a contiguous 1KB).

typedef __attribute__((ext_vector_type(8))) short short8;
typedef __attribute__((ext_vector_type(4))) float f32x4;

#define SCALE 0.17677669529663687f   // 32^-0.5

__device__ __forceinline__ unsigned short f2bf(float x) {
    union { float f; unsigned int i; } v; v.f = x;
    return (unsigned short)((v.i + 0x7FFFu + ((v.i >> 16) & 1u)) >> 16);
}

// XOR-swizzled index into a [R][32]-short buffer (row stride 64B = 4 x 16B slots).
__device__ __forceinline__ int swz32(int row, int col) {
    return row * 32 + ((((col >> 3) ^ (row & 3)) << 3) | (col & 7));
}
// XOR-swizzled index into a [R][64]-short buffer (row stride 128B = 8 x 16B slots).
__device__ __forceinline__ int swz64(int row, int col) {
    return row * 64 + ((((col >> 3) ^ (row & 7)) << 3) | (col & 7));
}

__global__ void repack_kernel(const float* __restrict__ wqkv,
                              const float* __restrict__ wproj,
                              unsigned short* __restrict__ wq_pack,
                              unsigned short* __restrict__ wp_pack) {
    int idx = blockIdx.x * 256 + threadIdx.x;
    if (idx < 6 * 576 * 32) {
        int kk  = idx & 31;
        int col = (idx >> 5) % 576;
        int kt  = idx / (576 * 32);
        wq_pack[idx] = f2bf(wqkv[(kt * 32 + kk) * 576 + col]);
    } else {
        int j = idx - 6 * 576 * 32;
        if (j < 6 * 192 * 32) {
            int kk  = j & 31;
            int col = (j >> 5) % 192;
            int kt  = j / (192 * 32);
            wp_pack[j] = f2bf(wproj[(kt * 32 + kk) * 192 + col]);
        }
    }
}

__global__ __launch_bounds__(384, 3)
void win_attn_kernel(const float* __restrict__ x,
                     const int* __restrict__ mask,
                     const float* __restrict__ bqkv,
                     const float* __restrict__ bproj,
                     const unsigned short* __restrict__ wq,
                     const unsigned short* __restrict__ wpj,
                     float* __restrict__ out) {
    // region unions: [phase1-2] x tile 64x200 (12800)  [phase3-5] per-head
    // swizzled bufs q[64][32] k[64][32] vt[32][64] (6144/head * 6 = 36864),
    // p[64][64] overlays q+k exactly.  [phase6] O_all 64x200 (12800)
    __shared__ __align__(16) unsigned short region[36864];
    __shared__ float mbias[64];

    const int b    = blockIdx.x;
    const int tid  = threadIdx.x;
    const int lane = tid & 63;
    const int h    = tid >> 6;      // wave index == head
    const int quad = lane >> 4;
    const int l16  = lane & 15;

    // ---------------- phase 1: stage x (fp32 -> bf16), pad, mask bias -----
    const float* xb = x + (size_t)b * 9408;
    for (int i4 = tid; i4 < 2352; i4 += 384) {   // 9408 elems / 4
        int flat = i4 * 4;
        int n = flat / 192, c = flat % 192;      // 192 % 4 == 0: no row cross
        float4 v = *(const float4*)(const void*)&xb[flat];
        ushort4 pk = make_ushort4(f2bf(v.x), f2bf(v.y), f2bf(v.z), f2bf(v.w));
        *(ushort4*)(void*)&region[n * 200 + c] = pk;
    }
    if (tid < 375) {                              // zero rows 49..63 (15*200)
        uint4 z = {0u, 0u, 0u, 0u};
        *(uint4*)(void*)&region[9800 + tid * 8] = z;
    }
    if (tid < 64)
        mbias[tid] = (tid < 49 && mask[b * 49 + tid] != 0) ? 0.0f : -1e30f;
    __syncthreads();

    // ---------------- phase 2: QKV GEMM --------------------------------
    f32x4 acc[6][4];
    #pragma unroll
    for (int t = 0; t < 6; ++t)
        #pragma unroll
        for (int mt = 0; mt < 4; ++mt)
            acc[t][mt] = (f32x4){0.f, 0.f, 0.f, 0.f};

    int colb[6];
    #pragma unroll
    for (int t = 0; t < 6; ++t) colb[t] = (t >> 1) * 192 + h * 32 + (t & 1) * 16;

    #pragma unroll
    for (int kt = 0; kt < 6; ++kt) {
        short8 af[4];
        #pragma unroll
        for (int mt = 0; mt < 4; ++mt)
            af[mt] = *(const short8*)(const void*)
                     &region[(mt * 16 + l16) * 200 + kt * 32 + quad * 8];
        #pragma unroll
        for (int t = 0; t < 6; ++t) {
            short8 bw = *(const short8*)(const void*)
                        &wq[(size_t)(kt * 576 + colb[t] + l16) * 32 + quad * 8];
            #pragma unroll
            for (int mt = 0; mt < 4; ++mt)
                acc[t][mt] = __builtin_amdgcn_mfma_f32_16x16x32_bf16(
                                 af[mt], bw, acc[t][mt], 0, 0, 0);
        }
    }
    #pragma unroll
    for (int t = 0; t < 6; ++t) {
        float bv = bqkv[colb[t] + l16];
        #pragma unroll
        for (int mt = 0; mt < 4; ++mt)
            #pragma unroll
            for (int r = 0; r < 4; ++r)
                acc[t][mt][r] += bv;
    }
    __syncthreads();   // all waves done reading x; region becomes head bufs

    // ---------------- phase 3: q,k row-major; v transposed ---------------
    unsigned short* qb  = &region[h * 6144];
    unsigned short* kb  = qb + 2048;   // k[64][32] swizzled
    unsigned short* vtb = qb + 4096;   // vt[32][64] swizzled
    #pragma unroll
    for (int t = 0; t < 2; ++t)
        #pragma unroll
        for (int mt = 0; mt < 4; ++mt)
            #pragma unroll
            for (int r = 0; r < 4; ++r) {
                int row = mt * 16 + quad * 4 + r;
                qb[swz32(row, t * 16 + l16)] = f2bf(acc[t    ][mt][r]);
                kb[swz32(row, t * 16 + l16)] = f2bf(acc[t + 2][mt][r]);
            }
    #pragma unroll
    for (int t = 0; t < 2; ++t)
        #pragma unroll
        for (int mt = 0; mt < 4; ++mt) {
            int d = t * 16 + l16;
            ushort4 pk = make_ushort4(f2bf(acc[4 + t][mt][0]), f2bf(acc[4 + t][mt][1]),
                                      f2bf(acc[4 + t][mt][2]), f2bf(acc[4 + t][mt][3]));
            *(ushort4*)(void*)&vtb[swz64(d, mt * 16 + quad * 4)] = pk;
        }
    // wave-local buffers; LDS ops within a wave are in-order -> no barrier

    // ---------------- phase 4: S = Q K^T, masked softmax -----------------
    f32x4 s[4][4];
    #pragma unroll
    for (int mt = 0; mt < 4; ++mt)
        #pragma unroll
        for (int nt = 0; nt < 4; ++nt)
            s[mt][nt] = (f32x4){0.f, 0.f, 0.f, 0.f};

    {
        short8 aq[4], bk[4];
        #pragma unroll
        for (int mt = 0; mt < 4; ++mt)
            aq[mt] = *(const short8*)(const void*)&qb[swz32(mt * 16 + l16, quad * 8)];
        #pragma unroll
        for (int nt = 0; nt < 4; ++nt)
            bk[nt] = *(const short8*)(const void*)&kb[swz32(nt * 16 + l16, quad * 8)];
        #pragma unroll
        for (int mt = 0; mt < 4; ++mt)
            #pragma unroll
            for (int nt = 0; nt < 4; ++nt)
                s[mt][nt] = __builtin_amdgcn_mfma_f32_16x16x32_bf16(
                                aq[mt], bk[nt], s[mt][nt], 0, 0, 0);
    }

    float mb[4];
    #pragma unroll
    for (int nt = 0; nt < 4; ++nt) mb[nt] = mbias[nt * 16 + l16];

    #pragma unroll
    for (int mt = 0; mt < 4; ++mt) {
        #pragma unroll
        for (int r = 0; r < 4; ++r) {
            float v0 = s[mt][0][r] * SCALE + mb[0];
            float v1 = s[mt][1][r] * SCALE + mb[1];
            float v2 = s[mt][2][r] * SCALE + mb[2];
            float v3 = s[mt][3][r] * SCALE + mb[3];
            float mx = fmaxf(fmaxf(v0, v1), fmaxf(v2, v3));
            mx = fmaxf(mx, __shfl_xor(mx, 1));
            mx = fmaxf(mx, __shfl_xor(mx, 2));
            mx = fmaxf(mx, __shfl_xor(mx, 4));
            mx = fmaxf(mx, __shfl_xor(mx, 8));
            float e0 = __expf(v0 - mx), e1 = __expf(v1 - mx);
            float e2 = __expf(v2 - mx), e3 = __expf(v3 - mx);
            float sum = e0 + e1 + e2 + e3;
            sum += __shfl_xor(sum, 1);
            sum += __shfl_xor(sum, 2);
            sum += __shfl_xor(sum, 4);
            sum += __shfl_xor(sum, 8);
            float inv = 1.0f / sum;
            s[mt][0][r] = e0 * inv; s[mt][1][r] = e1 * inv;
            s[mt][2][r] = e2 * inv; s[mt][3][r] = e3 * inv;
        }
    }

    // P -> LDS in A-layout (overlays q and k exactly; q/k reads already done)
    unsigned short* pb = qb;   // p[64][64] swizzled: 4096 == q+k (2048+2048)
    #pragma unroll
    for (int mt = 0; mt < 4; ++mt)
        #pragma unroll
        for (int nt = 0; nt < 4; ++nt)
            #pragma unroll
            for (int r = 0; r < 4; ++r)
                pb[swz64(mt * 16 + quad * 4 + r, nt * 16 + l16)] = f2bf(s[mt][nt][r]);

    // ---------------- phase 5: O = P V -----------------------------------
    f32x4 o[4][2];
    #pragma unroll
    for (int mt = 0; mt < 4; ++mt)
        #pragma unroll
        for (int dt = 0; dt < 2; ++dt)
            o[mt][dt] = (f32x4){0.f, 0.f, 0.f, 0.f};

    #pragma unroll
    for (int kt = 0; kt < 2; ++kt) {
        short8 ap[4], bv[2];
        #pragma unroll
        for (int mt = 0; mt < 4; ++mt)
            ap[mt] = *(const short8*)(const void*)
                     &pb[swz64(mt * 16 + l16, kt * 32 + quad * 8)];
        #pragma unroll
        for (int dt = 0; dt < 2; ++dt)
            bv[dt] = *(const short8*)(const void*)
                     &vtb[swz64(dt * 16 + l16, kt * 32 + quad * 8)];
        #pragma unroll
        for (int mt = 0; mt < 4; ++mt)
            #pragma unroll
            for (int dt = 0; dt < 2; ++dt)
                o[mt][dt] = __builtin_amdgcn_mfma_f32_16x16x32_bf16(
                                ap[mt], bv[dt], o[mt][dt], 0, 0, 0);
    }

    __syncthreads();   // all waves done with attn bufs; region becomes O_all
    #pragma unroll
    for (int dt = 0; dt < 2; ++dt)
        #pragma unroll
        for (int mt = 0; mt < 4; ++mt)
            #pragma unroll
            for (int r = 0; r < 4; ++r)
                region[(mt * 16 + quad * 4 + r) * 200 + h * 32 + dt * 16 + l16]
                    = f2bf(o[mt][dt][r]);
    __syncthreads();

    // ---------------- phase 6: projection GEMM + bias + fp32 store -------
    f32x4 po[2][4];
    #pragma unroll
    for (int nt = 0; nt < 2; ++nt)
        #pragma unroll
        for (int mt = 0; mt < 4; ++mt)
            po[nt][mt] = (f32x4){0.f, 0.f, 0.f, 0.f};

    #pragma unroll
    for (int kt = 0; kt < 6; ++kt) {
        short8 ao[4];
        #pragma unroll
        for (int mt = 0; mt < 4; ++mt)
            ao[mt] = *(const short8*)(const void*)
                     &region[(mt * 16 + l16) * 200 + kt * 32 + quad * 8];
        #pragma unroll
        for (int nt = 0; nt < 2; ++nt) {
            int col = h * 32 + nt * 16 + l16;
            short8 bw = *(const short8*)(const void*)
                        &wpj[(size_t)(kt * 192 + col) * 32 + quad * 8];
            #pragma unroll
            for (int mt = 0; mt < 4; ++mt)
                po[nt][mt] = __builtin_amdgcn_mfma_f32_16x16x32_bf16(
                                 ao[mt], bw, po[nt][mt], 0, 0, 0);
        }
    }

    #pragma unroll
    for (int nt = 0; nt < 2; ++nt) {
        int col = h * 32 + nt * 16 + l16;
        float bv = bproj[col];
        #pragma unroll
        for (int mt = 0; mt < 4; ++mt)
            #pragma unroll
            for (int r = 0; r < 4; ++r) {
                int row = mt * 16 + quad * 4 + r;
                if (row < 49)
                    out[(size_t)b * 9408 + row * 192 + col] = po[nt][mt][r] + bv;
            }
    }
}

extern "C" void kernel_launch(void* const* d_in, const int* in_sizes, int n_in,
                              void* d_out, int out_size, void* d_ws, size_t ws_size,
                              hipStream_t stream) {
    const float* x      = (const float*)d_in[0];
    const int*   mask   = (const int*)d_in[1];
    const float* w_qkv  = (const float*)d_in[2];
    const float* b_qkv  = (const float*)d_in[3];
    const float* w_proj = (const float*)d_in[4];
    const float* b_proj = (const float*)d_in[5];
    float*       out    = (float*)d_out;

    unsigned short* wq_pack = (unsigned short*)d_ws;          // 110592 elems
    unsigned short* wp_pack = wq_pack + 110592;               //  36864 elems

    repack_kernel<<<(110592 + 36864 + 255) / 256, 256, 0, stream>>>(
        w_qkv, w_proj, wq_pack, wp_pack);
    win_attn_kernel<<<8192, 384, 0, stream>>>(x, mask, b_qkv, b_proj,
                                              wq_pack, wp_pack, out);
}

// Round 2
// 850.376 us; speedup vs baseline: 1.1685x; 1.1685x over previous
//
#include <hip/hip_runtime.h>

// Fused windowed multi-head attention for MI355X (gfx950).
// B=8192 windows, N=49 tokens, C=192, H=6 heads, HD=32.
// Inputs/outputs are FP32 (per reference); mask int32. Interior compute bf16 MFMA.
//
// Structure: 1 block per window, 6 waves (one per head).
//   phase 1: stage x fp32 -> bf16 (49x192 -> 64x200 padded) + mask bias in LDS
//   phase 2: QKV GEMM. q,k tiles use SWAPPED operands mfma(W,X) -> Q^T/K^T in
//            C-layout; v tiles normal mfma(X,W).
//   phase 3: v^T -> per-head LDS buffer (XOR-swizzled), cvt_pk_bf16 pairs
//   phase 4: Q,K C-layout -> A/B fragments via in-register quad-shuffle
//            (ds_bpermute + cndmask + v_cvt_pk_bf16_f32); S^T = mfma(K,Q);
//            masked softmax with lane-local q-rows (2 shfl_xor only);
//            P^T -> A-fragments via the same quad-shuffle. NO q/k/p LDS.
//   phase 5: O = P V (v^T from LDS as B operand)
//   phase 6: O tile (64x192) to LDS, cooperative projection GEMM + bias, store
//
// v3 (occupancy + op count): q/k/p LDS buffers eliminated -> LDS 74.2KB -> 50.4KB
// (empirical: 74KB still co-scheduled only 1 block/CU; <=64KB is required for 2).
// vt region disjoint from x-tile -> post-QKV barrier deleted (phases 2-5 are
// barrier-free, wave-independent). Plain __launch_bounds__(384): v2's (384,3)
// drove VGPR to 84 (=512/6 budget) with ~57B/thread scratch spill traffic
// (+173MB HBM writes).
//
// Weights repacked each call fp32 -> bf16 in B-fragment-contiguous layout:
// wp[(kt*COLS + col)*32 + kk] = w[(kt*32+kk)*COLS + col].

typedef __attribute__((ext_vector_type(8))) short short8;
typedef __attribute__((ext_vector_type(4))) float f32x4;

#define SCALE 0.17677669529663687f   // 32^-0.5

__device__ __forceinline__ unsigned short f2bf(float x) {
    union { float f; unsigned int i; } v; v.f = x;
    return (unsigned short)((v.i + 0x7FFFu + ((v.i >> 16) & 1u)) >> 16);
}

// packed f32x2 -> bf16x2 (RNE), 1 instr
__device__ __forceinline__ unsigned int pkbf(float lo, float hi) {
    unsigned int r;
    asm("v_cvt_pk_bf16_f32 %0, %1, %2" : "=v"(r) : "v"(lo), "v"(hi));
    return r;
}

// XOR-swizzled index into a [R][64]-short buffer (row stride 128B = 8 x 16B slots).
__device__ __forceinline__ int swz64(int row, int col) {
    return row * 64 + ((((col >> 3) ^ (row & 7)) << 3) | (col & 7));
}

// C-layout pair (two 16-row tiles: tlo = dims/k 0..15, thi = 16..31) ->
// A/B MFMA fragment. dst lane (quad,l16) elem e needs src reg r=e&3 from
// lane ((quad&1)*2 + (e>>2))*16 + l16, tile selected by quad>>1.
__device__ __forceinline__ short8 xpose(f32x4 tlo, f32x4 thi, int srcA, bool hi) {
    unsigned int pl0 = pkbf(tlo[0], tlo[1]);
    unsigned int pl1 = pkbf(tlo[2], tlo[3]);
    unsigned int ph0 = pkbf(thi[0], thi[1]);
    unsigned int ph1 = pkbf(thi[2], thi[3]);
    unsigned int a0 = (unsigned int)__shfl((int)pl0, srcA);
    unsigned int b0 = (unsigned int)__shfl((int)ph0, srcA);
    unsigned int a1 = (unsigned int)__shfl((int)pl1, srcA);
    unsigned int b1 = (unsigned int)__shfl((int)ph1, srcA);
    unsigned int a2 = (unsigned int)__shfl((int)pl0, srcA + 16);
    unsigned int b2 = (unsigned int)__shfl((int)ph0, srcA + 16);
    unsigned int a3 = (unsigned int)__shfl((int)pl1, srcA + 16);
    unsigned int b3 = (unsigned int)__shfl((int)ph1, srcA + 16);
    union { short8 s8; unsigned int u[4]; } f;
    f.u[0] = hi ? b0 : a0;
    f.u[1] = hi ? b1 : a1;
    f.u[2] = hi ? b2 : a2;
    f.u[3] = hi ? b3 : a3;
    return f.s8;
}

__global__ void repack_kernel(const float* __restrict__ wqkv,
                              const float* __restrict__ wproj,
                              unsigned short* __restrict__ wq_pack,
                              unsigned short* __restrict__ wp_pack) {
    int idx = blockIdx.x * 256 + threadIdx.x;
    if (idx < 6 * 576 * 32) {
        int kk  = idx & 31;
        int col = (idx >> 5) % 576;
        int kt  = idx / (576 * 32);
        wq_pack[idx] = f2bf(wqkv[(kt * 32 + kk) * 576 + col]);
    } else {
        int j = idx - 6 * 576 * 32;
        if (j < 6 * 192 * 32) {
            int kk  = j & 31;
            int col = (j >> 5) % 192;
            int kt  = j / (192 * 32);
            wp_pack[j] = f2bf(wproj[(kt * 32 + kk) * 192 + col]);
        }
    }
}

__global__ __launch_bounds__(384)
void win_attn_kernel(const float* __restrict__ x,
                     const int* __restrict__ mask,
                     const float* __restrict__ bqkv,
                     const float* __restrict__ bproj,
                     const unsigned short* __restrict__ wq,
                     const unsigned short* __restrict__ wpj,
                     float* __restrict__ out) {
    // region: [0..12800)  x tile 64x200 (phases 1-2), later O_all 64x200 (phase 6)
    //         [12800..25088) per-head vt[32][64] swizzled (6 x 2048), phases 3-5
    // vt is DISJOINT from the x tile -> no barrier between phase 2 and 3-5.
    __shared__ __align__(16) unsigned short region[25088];
    __shared__ __align__(16) float mbias[64];

    const int b    = blockIdx.x;
    const int tid  = threadIdx.x;
    const int lane = tid & 63;
    const int h    = tid >> 6;      // wave index == head
    const int quad = lane >> 4;
    const int l16  = lane & 15;

    // ---------------- phase 1: stage x (fp32 -> bf16), pad, mask bias -----
    const float* xb = x + (size_t)b * 9408;
    for (int i4 = tid; i4 < 2352; i4 += 384) {   // 9408 elems / 4
        int flat = i4 * 4;
        int n = flat / 192, c = flat % 192;      // 192 % 4 == 0: no row cross
        float4 v = *(const float4*)(const void*)&xb[flat];
        uint2 pk;
        pk.x = pkbf(v.x, v.y);
        pk.y = pkbf(v.z, v.w);
        *(uint2*)(void*)&region[n * 200 + c] = pk;
    }
    if (tid < 375) {                              // zero rows 49..63 (15*200)
        uint4 z = {0u, 0u, 0u, 0u};
        *(uint4*)(void*)&region[9800 + tid * 8] = z;
    }
    if (tid < 64)
        mbias[tid] = (tid < 49 && mask[b * 49 + tid] != 0) ? 0.0f : -1e30f;
    __syncthreads();

    // ---------------- phase 2: QKV GEMM --------------------------------
    // t=0..3 (q,k): swapped operands -> acc[t][nt]: lane holds
    //   Y[token=nt*16+l16][outcol = colb[t]+quad*4+r]
    // t=4..5 (v): normal -> acc[t][mt]: lane holds
    //   V[token=mt*16+quad*4+r][dim=(t-4)*16+l16]
    f32x4 acc[6][4];
    #pragma unroll
    for (int t = 0; t < 6; ++t)
        #pragma unroll
        for (int mt = 0; mt < 4; ++mt)
            acc[t][mt] = (f32x4){0.f, 0.f, 0.f, 0.f};

    int colb[6];
    #pragma unroll
    for (int t = 0; t < 6; ++t) colb[t] = (t >> 1) * 192 + h * 32 + (t & 1) * 16;

    #pragma unroll
    for (int kt = 0; kt < 6; ++kt) {
        short8 af[4];
        #pragma unroll
        for (int mt = 0; mt < 4; ++mt)
            af[mt] = *(const short8*)(const void*)
                     &region[(mt * 16 + l16) * 200 + kt * 32 + quad * 8];
        #pragma unroll
        for (int t = 0; t < 6; ++t) {
            short8 bw = *(const short8*)(const void*)
                        &wq[(size_t)(kt * 576 + colb[t] + l16) * 32 + quad * 8];
            #pragma unroll
            for (int mt = 0; mt < 4; ++mt) {
                if (t < 4)
                    acc[t][mt] = __builtin_amdgcn_mfma_f32_16x16x32_bf16(
                                     bw, af[mt], acc[t][mt], 0, 0, 0);
                else
                    acc[t][mt] = __builtin_amdgcn_mfma_f32_16x16x32_bf16(
                                     af[mt], bw, acc[t][mt], 0, 0, 0);
            }
        }
    }
    // bias: q,k outcol = colb[t]+quad*4+r ; v outcol = colb[t]+l16
    #pragma unroll
    for (int t = 0; t < 4; ++t) {
        f32x4 bq = *(const f32x4*)(const void*)&bqkv[colb[t] + quad * 4];
        #pragma unroll
        for (int nt = 0; nt < 4; ++nt)
            #pragma unroll
            for (int r = 0; r < 4; ++r)
                acc[t][nt][r] += bq[r];
    }
    #pragma unroll
    for (int t = 4; t < 6; ++t) {
        float bv = bqkv[colb[t] + l16];
        #pragma unroll
        for (int mt = 0; mt < 4; ++mt)
            #pragma unroll
            for (int r = 0; r < 4; ++r)
                acc[t][mt][r] += bv;
    }
    // NO barrier: vt region disjoint from x tile; phases 3-5 are wave-local.

    // ---------------- phase 3: v transposed to LDS ------------------------
    unsigned short* vtb = &region[12800 + h * 2048];   // vt[32][64] swizzled
    #pragma unroll
    for (int t = 0; t < 2; ++t)
        #pragma unroll
        for (int mt = 0; mt < 4; ++mt) {
            int d = t * 16 + l16;
            uint2 pk;
            pk.x = pkbf(acc[4 + t][mt][0], acc[4 + t][mt][1]);
            pk.y = pkbf(acc[4 + t][mt][2], acc[4 + t][mt][3]);
            *(uint2*)(void*)&vtb[swz64(d, mt * 16 + quad * 4)] = pk;
        }

    // ---------------- phase 4: fragments, S^T = K Q^T, masked softmax -----
    const int  srcA = ((lane & 16) << 1) | l16;   // ((quad&1)*2)*16 + l16
    const bool hiq  = (lane & 32) != 0;           // quad>>1

    short8 qf[4], kf[4];
    #pragma unroll
    for (int nt = 0; nt < 4; ++nt) {
        qf[nt] = xpose(acc[0][nt], acc[1][nt], srcA, hiq);
        kf[nt] = xpose(acc[2][nt], acc[3][nt], srcA, hiq);
    }

    // s[mt_k][nt_q]: lane holds S[q=nt*16+l16][k=mt*16+quad*4+r]
    f32x4 s[4][4];
    #pragma unroll
    for (int mt = 0; mt < 4; ++mt)
        #pragma unroll
        for (int nt = 0; nt < 4; ++nt)
            s[mt][nt] = (f32x4){0.f, 0.f, 0.f, 0.f};
    #pragma unroll
    for (int mt = 0; mt < 4; ++mt)
        #pragma unroll
        for (int nt = 0; nt < 4; ++nt)
            s[mt][nt] = __builtin_amdgcn_mfma_f32_16x16x32_bf16(
                            kf[mt], qf[nt], s[mt][nt], 0, 0, 0);

    f32x4 mb4[4];
    #pragma unroll
    for (int mt = 0; mt < 4; ++mt)
        mb4[mt] = *(const f32x4*)(const void*)&mbias[mt * 16 + quad * 4];

    #pragma unroll
    for (int nt = 0; nt < 4; ++nt) {
        float ev[4][4];
        float pm[4];
        #pragma unroll
        for (int mt = 0; mt < 4; ++mt) {
            #pragma unroll
            for (int r = 0; r < 4; ++r)
                ev[mt][r] = s[mt][nt][r] * SCALE + mb4[mt][r];
            pm[mt] = fmaxf(fmaxf(ev[mt][0], ev[mt][1]),
                           fmaxf(ev[mt][2], ev[mt][3]));
        }
        float mx = fmaxf(fmaxf(pm[0], pm[1]), fmaxf(pm[2], pm[3]));
        mx = fmaxf(mx, __shfl_xor(mx, 16));
        mx = fmaxf(mx, __shfl_xor(mx, 32));
        float ps[4];
        #pragma unroll
        for (int mt = 0; mt < 4; ++mt) {
            #pragma unroll
            for (int r = 0; r < 4; ++r)
                ev[mt][r] = __expf(ev[mt][r] - mx);
            ps[mt] = (ev[mt][0] + ev[mt][1]) + (ev[mt][2] + ev[mt][3]);
        }
        float sum = (ps[0] + ps[1]) + (ps[2] + ps[3]);
        sum += __shfl_xor(sum, 16);
        sum += __shfl_xor(sum, 32);
        float inv = 1.0f / sum;
        #pragma unroll
        for (int mt = 0; mt < 4; ++mt)
            #pragma unroll
            for (int r = 0; r < 4; ++r)
                s[mt][nt][r] = ev[mt][r] * inv;
    }

    // P^T -> A-fragments, same quad-shuffle (no LDS round-trip)
    short8 ap[4][2];
    #pragma unroll
    for (int mo = 0; mo < 4; ++mo)
        #pragma unroll
        for (int kt = 0; kt < 2; ++kt)
            ap[mo][kt] = xpose(s[kt * 2][mo], s[kt * 2 + 1][mo], srcA, hiq);

    // ---------------- phase 5: O = P V -----------------------------------
    f32x4 o[4][2];
    #pragma unroll
    for (int mo = 0; mo < 4; ++mo)
        #pragma unroll
        for (int dt = 0; dt < 2; ++dt)
            o[mo][dt] = (f32x4){0.f, 0.f, 0.f, 0.f};

    #pragma unroll
    for (int kt = 0; kt < 2; ++kt) {
        short8 bvv[2];
        #pragma unroll
        for (int dt = 0; dt < 2; ++dt)
            bvv[dt] = *(const short8*)(const void*)
                      &vtb[swz64(dt * 16 + l16, kt * 32 + quad * 8)];
        #pragma unroll
        for (int mo = 0; mo < 4; ++mo)
            #pragma unroll
            for (int dt = 0; dt < 2; ++dt)
                o[mo][dt] = __builtin_amdgcn_mfma_f32_16x16x32_bf16(
                                ap[mo][kt], bvv[dt], o[mo][dt], 0, 0, 0);
    }

    __syncthreads();   // all waves past phase-2 x reads; region[0..] becomes O_all
    #pragma unroll
    for (int dt = 0; dt < 2; ++dt)
        #pragma unroll
        for (int mt = 0; mt < 4; ++mt)
            #pragma unroll
            for (int r = 0; r < 4; ++r)
                region[(mt * 16 + quad * 4 + r) * 200 + h * 32 + dt * 16 + l16]
                    = f2bf(o[mt][dt][r]);
    __syncthreads();

    // ---------------- phase 6: projection GEMM + bias + fp32 store -------
    f32x4 po[2][4];
    #pragma unroll
    for (int nt = 0; nt < 2; ++nt)
        #pragma unroll
        for (int mt = 0; mt < 4; ++mt)
            po[nt][mt] = (f32x4){0.f, 0.f, 0.f, 0.f};

    #pragma unroll
    for (int kt = 0; kt < 6; ++kt) {
        short8 ao[4];
        #pragma unroll
        for (int mt = 0; mt < 4; ++mt)
            ao[mt] = *(const short8*)(const void*)
                     &region[(mt * 16 + l16) * 200 + kt * 32 + quad * 8];
        #pragma unroll
        for (int nt = 0; nt < 2; ++nt) {
            int col = h * 32 + nt * 16 + l16;
            short8 bw = *(const short8*)(const void*)
                        &wpj[(size_t)(kt * 192 + col) * 32 + quad * 8];
            #pragma unroll
            for (int mt = 0; mt < 4; ++mt)
                po[nt][mt] = __builtin_amdgcn_mfma_f32_16x16x32_bf16(
                                 ao[mt], bw, po[nt][mt], 0, 0, 0);
        }
    }

    #pragma unroll
    for (int nt = 0; nt < 2; ++nt) {
        int col = h * 32 + nt * 16 + l16;
        float bv = bproj[col];
        #pragma unroll
        for (int mt = 0; mt < 4; ++mt)
            #pragma unroll
            for (int r = 0; r < 4; ++r) {
                int row = mt * 16 + quad * 4 + r;
                if (row < 49)
                    out[(size_t)b * 9408 + row * 192 + col] = po[nt][mt][r] + bv;
            }
    }
}

extern "C" void kernel_launch(void* const* d_in, const int* in_sizes, int n_in,
                              void* d_out, int out_size, void* d_ws, size_t ws_size,
                              hipStream_t stream) {
    const float* x      = (const float*)d_in[0];
    const int*   mask   = (const int*)d_in[1];
    const float* w_qkv  = (const float*)d_in[2];
    const float* b_qkv  = (const float*)d_in[3];
    const float* w_proj = (const float*)d_in[4];
    const float* b_proj = (const float*)d_in[5];
    float*       out    = (float*)d_out;

    unsigned short* wq_pack = (unsigned short*)d_ws;          // 110592 elems
    unsigned short* wp_pack = wq_pack + 110592;               //  36864 elems

    repack_kernel<<<(110592 + 36864 + 255) / 256, 256, 0, stream>>>(
        w_qkv, w_proj, wq_pack, wp_pack);
    win_attn_kernel<<<8192, 384, 0, stream>>>(x, mask, b_qkv, b_proj,
                                              wq_pack, wp_pack, out);
}

// Round 3
// 848.733 us; speedup vs baseline: 1.1708x; 1.0019x over previous
//
#include <hip/hip_runtime.h>

// Fused windowed multi-head attention for MI355X (gfx950).
// B=8192 windows, N=49 tokens, C=192, H=6 heads, HD=32.
// Inputs/outputs are FP32 (per reference); mask int32. Interior compute bf16 MFMA.
//
// Structure: 1 block per window, 6 waves (one per head).
//   phase 1: stage x fp32 -> bf16 (49x192 -> 64x200 padded) + mask bias in LDS
//   phase 2a: Q,K GEMM pass (swapped operands mfma(W,X) -> Q^T/K^T C-layout),
//             collapsed immediately to bf16 A/B fragments via quad-shuffle xpose.
//   phase 2b: V GEMM pass (normal operands), v^T -> per-head swizzled LDS.
//   phase 4: per-column-tile fused { S^T slice = mfma(K,Q); masked softmax
//            (lane-local q-rows, 2 shfl_xor); xpose -> P A-fragment }.
//            No q/k/s/p arrays live across the loop. NO q/k/p LDS.
//   phase 5: O = P V (v^T from LDS as B operand)
//   phase 6: O tile (64x192) to LDS, cooperative projection GEMM + bias, store
//
// v4 (register pressure): occupancy was stuck at 17.7% (=1 block/CU, 6 waves)
// across LDS 89.6/74.2/50.7 KB -> LDS is not the limiter. Theory: VGPR 88 +
// ~96 AGPR (acc[6][4]) = ~184 regs/wave -> 2 waves/SIMD -> a second 6-wave
// block cannot co-schedule. This version splits QKV into q+k / v passes
// (peak acc 64 regs) and fuses softmax per-slice (no s[4][4]), targeting
// <=~130 total regs -> 3-4 waves/SIMD -> 2 blocks/CU.
//
// Weights repacked each call fp32 -> bf16 in B-fragment-contiguous layout:
// wp[(kt*COLS + col)*32 + kk] = w[(kt*32+kk)*COLS + col].

typedef __attribute__((ext_vector_type(8))) short short8;
typedef __attribute__((ext_vector_type(4))) float f32x4;

#define SCALE 0.17677669529663687f   // 32^-0.5

__device__ __forceinline__ unsigned short f2bf(float x) {
    union { float f; unsigned int i; } v; v.f = x;
    return (unsigned short)((v.i + 0x7FFFu + ((v.i >> 16) & 1u)) >> 16);
}

// packed f32x2 -> bf16x2 (RNE), 1 instr
__device__ __forceinline__ unsigned int pkbf(float lo, float hi) {
    unsigned int r;
    asm("v_cvt_pk_bf16_f32 %0, %1, %2" : "=v"(r) : "v"(lo), "v"(hi));
    return r;
}

// XOR-swizzled index into a [R][64]-short buffer (row stride 128B = 8 x 16B slots).
__device__ __forceinline__ int swz64(int row, int col) {
    return row * 64 + ((((col >> 3) ^ (row & 7)) << 3) | (col & 7));
}

// C-layout pair (two 16-row tiles: tlo = dims/k 0..15, thi = 16..31) ->
// A/B MFMA fragment. dst lane (quad,l16) elem e needs src reg r=e&3 from
// lane ((quad&1)*2 + (e>>2))*16 + l16, tile selected by quad>>1.
__device__ __forceinline__ short8 xpose(f32x4 tlo, f32x4 thi, int srcA, bool hi) {
    unsigned int pl0 = pkbf(tlo[0], tlo[1]);
    unsigned int pl1 = pkbf(tlo[2], tlo[3]);
    unsigned int ph0 = pkbf(thi[0], thi[1]);
    unsigned int ph1 = pkbf(thi[2], thi[3]);
    unsigned int a0 = (unsigned int)__shfl((int)pl0, srcA);
    unsigned int b0 = (unsigned int)__shfl((int)ph0, srcA);
    unsigned int a1 = (unsigned int)__shfl((int)pl1, srcA);
    unsigned int b1 = (unsigned int)__shfl((int)ph1, srcA);
    unsigned int a2 = (unsigned int)__shfl((int)pl0, srcA + 16);
    unsigned int b2 = (unsigned int)__shfl((int)ph0, srcA + 16);
    unsigned int a3 = (unsigned int)__shfl((int)pl1, srcA + 16);
    unsigned int b3 = (unsigned int)__shfl((int)ph1, srcA + 16);
    union { short8 s8; unsigned int u[4]; } f;
    f.u[0] = hi ? b0 : a0;
    f.u[1] = hi ? b1 : a1;
    f.u[2] = hi ? b2 : a2;
    f.u[3] = hi ? b3 : a3;
    return f.s8;
}

__global__ void repack_kernel(const float* __restrict__ wqkv,
                              const float* __restrict__ wproj,
                              unsigned short* __restrict__ wq_pack,
                              unsigned short* __restrict__ wp_pack) {
    int idx = blockIdx.x * 256 + threadIdx.x;
    if (idx < 6 * 576 * 32) {
        int kk  = idx & 31;
        int col = (idx >> 5) % 576;
        int kt  = idx / (576 * 32);
        wq_pack[idx] = f2bf(wqkv[(kt * 32 + kk) * 576 + col]);
    } else {
        int j = idx - 6 * 576 * 32;
        if (j < 6 * 192 * 32) {
            int kk  = j & 31;
            int col = (j >> 5) % 192;
            int kt  = j / (192 * 32);
            wp_pack[j] = f2bf(wproj[(kt * 32 + kk) * 192 + col]);
        }
    }
}

__global__ __launch_bounds__(384)
void win_attn_kernel(const float* __restrict__ x,
                     const int* __restrict__ mask,
                     const float* __restrict__ bqkv,
                     const float* __restrict__ bproj,
                     const unsigned short* __restrict__ wq,
                     const unsigned short* __restrict__ wpj,
                     float* __restrict__ out) {
    // region: [0..12800)  x tile 64x200 (phases 1-2), later O_all 64x200 (phase 6)
    //         [12800..25088) per-head vt[32][64] swizzled (6 x 2048), phases 3-5
    // vt is DISJOINT from the x tile -> no barrier between phase 2 and 3-5.
    __shared__ __align__(16) unsigned short region[25088];
    __shared__ __align__(16) float mbias[64];

    const int b    = blockIdx.x;
    const int tid  = threadIdx.x;
    const int lane = tid & 63;
    const int h    = tid >> 6;      // wave index == head
    const int quad = lane >> 4;
    const int l16  = lane & 15;

    // ---------------- phase 1: stage x (fp32 -> bf16), pad, mask bias -----
    const float* xb = x + (size_t)b * 9408;
    for (int i4 = tid; i4 < 2352; i4 += 384) {   // 9408 elems / 4
        int flat = i4 * 4;
        int n = flat / 192, c = flat % 192;      // 192 % 4 == 0: no row cross
        float4 v = *(const float4*)(const void*)&xb[flat];
        uint2 pk;
        pk.x = pkbf(v.x, v.y);
        pk.y = pkbf(v.z, v.w);
        *(uint2*)(void*)&region[n * 200 + c] = pk;
    }
    if (tid < 375) {                              // zero rows 49..63 (15*200)
        uint4 z = {0u, 0u, 0u, 0u};
        *(uint4*)(void*)&region[9800 + tid * 8] = z;
    }
    if (tid < 64)
        mbias[tid] = (tid < 49 && mask[b * 49 + tid] != 0) ? 0.0f : -1e30f;
    __syncthreads();

    const int  srcA = ((lane & 16) << 1) | l16;   // ((quad&1)*2)*16 + l16
    const bool hiq  = (lane & 32) != 0;           // quad>>1

    int colb[6];
    #pragma unroll
    for (int t = 0; t < 6; ++t) colb[t] = (t >> 1) * 192 + h * 32 + (t & 1) * 16;

    // ---------------- phase 2a: Q,K GEMM (swapped operands) ---------------
    // acc[t][nt]: lane holds Y[token=nt*16+l16][outcol = colb[t]+quad*4+r]
    short8 qf[4], kf[4];
    {
        f32x4 acc[4][4];
        #pragma unroll
        for (int t = 0; t < 4; ++t)
            #pragma unroll
            for (int mt = 0; mt < 4; ++mt)
                acc[t][mt] = (f32x4){0.f, 0.f, 0.f, 0.f};

        #pragma unroll
        for (int kt = 0; kt < 6; ++kt) {
            short8 af[4];
            #pragma unroll
            for (int mt = 0; mt < 4; ++mt)
                af[mt] = *(const short8*)(const void*)
                         &region[(mt * 16 + l16) * 200 + kt * 32 + quad * 8];
            #pragma unroll
            for (int t = 0; t < 4; ++t) {
                short8 bw = *(const short8*)(const void*)
                            &wq[(size_t)(kt * 576 + colb[t] + l16) * 32 + quad * 8];
                #pragma unroll
                for (int mt = 0; mt < 4; ++mt)
                    acc[t][mt] = __builtin_amdgcn_mfma_f32_16x16x32_bf16(
                                     bw, af[mt], acc[t][mt], 0, 0, 0);
            }
        }
        // bias: outcol = colb[t] + quad*4 + r
        #pragma unroll
        for (int t = 0; t < 4; ++t) {
            f32x4 bq = *(const f32x4*)(const void*)&bqkv[colb[t] + quad * 4];
            #pragma unroll
            for (int nt = 0; nt < 4; ++nt)
                #pragma unroll
                for (int r = 0; r < 4; ++r)
                    acc[t][nt][r] += bq[r];
        }
        // collapse to bf16 fragments immediately (frees 64 f32 regs)
        #pragma unroll
        for (int nt = 0; nt < 4; ++nt) {
            qf[nt] = xpose(acc[0][nt], acc[1][nt], srcA, hiq);
            kf[nt] = xpose(acc[2][nt], acc[3][nt], srcA, hiq);
        }
    }

    // ---------------- phase 2b: V GEMM (normal operands) + vt -> LDS ------
    unsigned short* vtb = &region[12800 + h * 2048];   // vt[32][64] swizzled
    {
        f32x4 accv[2][4];
        #pragma unroll
        for (int t = 0; t < 2; ++t)
            #pragma unroll
            for (int mt = 0; mt < 4; ++mt)
                accv[t][mt] = (f32x4){0.f, 0.f, 0.f, 0.f};

        #pragma unroll
        for (int kt = 0; kt < 6; ++kt) {
            short8 af[4];
            #pragma unroll
            for (int mt = 0; mt < 4; ++mt)
                af[mt] = *(const short8*)(const void*)
                         &region[(mt * 16 + l16) * 200 + kt * 32 + quad * 8];
            #pragma unroll
            for (int t = 0; t < 2; ++t) {
                short8 bw = *(const short8*)(const void*)
                            &wq[(size_t)(kt * 576 + colb[4 + t] + l16) * 32 + quad * 8];
                #pragma unroll
                for (int mt = 0; mt < 4; ++mt)
                    accv[t][mt] = __builtin_amdgcn_mfma_f32_16x16x32_bf16(
                                      af[mt], bw, accv[t][mt], 0, 0, 0);
            }
        }
        // bias (outcol = colb[4+t]+l16) and store v^T (swizzled)
        #pragma unroll
        for (int t = 0; t < 2; ++t) {
            float bv = bqkv[colb[4 + t] + l16];
            #pragma unroll
            for (int mt = 0; mt < 4; ++mt) {
                int d = t * 16 + l16;
                uint2 pk;
                pk.x = pkbf(accv[t][mt][0] + bv, accv[t][mt][1] + bv);
                pk.y = pkbf(accv[t][mt][2] + bv, accv[t][mt][3] + bv);
                *(uint2*)(void*)&vtb[swz64(d, mt * 16 + quad * 4)] = pk;
            }
        }
    }
    // NO barrier: vt region disjoint from x tile; phases 4-5 are wave-local.

    // ---------------- phase 4: per-slice S^T + masked softmax + P-frag ----
    f32x4 mb4[4];
    #pragma unroll
    for (int mt = 0; mt < 4; ++mt)
        mb4[mt] = *(const f32x4*)(const void*)&mbias[mt * 16 + quad * 4];

    short8 ap[4][2];
    #pragma unroll
    for (int nt = 0; nt < 4; ++nt) {
        // sr[mt]: lane holds S[q=nt*16+l16][k=mt*16+quad*4+r]
        f32x4 sr[4];
        #pragma unroll
        for (int mt = 0; mt < 4; ++mt) {
            sr[mt] = (f32x4){0.f, 0.f, 0.f, 0.f};
            sr[mt] = __builtin_amdgcn_mfma_f32_16x16x32_bf16(
                         kf[mt], qf[nt], sr[mt], 0, 0, 0);
        }
        float pm[4];
        #pragma unroll
        for (int mt = 0; mt < 4; ++mt) {
            #pragma unroll
            for (int r = 0; r < 4; ++r)
                sr[mt][r] = sr[mt][r] * SCALE + mb4[mt][r];
            pm[mt] = fmaxf(fmaxf(sr[mt][0], sr[mt][1]),
                           fmaxf(sr[mt][2], sr[mt][3]));
        }
        float mx = fmaxf(fmaxf(pm[0], pm[1]), fmaxf(pm[2], pm[3]));
        mx = fmaxf(mx, __shfl_xor(mx, 16));
        mx = fmaxf(mx, __shfl_xor(mx, 32));
        float ps[4];
        #pragma unroll
        for (int mt = 0; mt < 4; ++mt) {
            #pragma unroll
            for (int r = 0; r < 4; ++r)
                sr[mt][r] = __expf(sr[mt][r] - mx);
            ps[mt] = (sr[mt][0] + sr[mt][1]) + (sr[mt][2] + sr[mt][3]);
        }
        float sum = (ps[0] + ps[1]) + (ps[2] + ps[3]);
        sum += __shfl_xor(sum, 16);
        sum += __shfl_xor(sum, 32);
        float inv = 1.0f / sum;
        #pragma unroll
        for (int mt = 0; mt < 4; ++mt)
            #pragma unroll
            for (int r = 0; r < 4; ++r)
                sr[mt][r] *= inv;
        // P^T slice -> A-fragments (no LDS round-trip)
        ap[nt][0] = xpose(sr[0], sr[1], srcA, hiq);
        ap[nt][1] = xpose(sr[2], sr[3], srcA, hiq);
    }

    // ---------------- phase 5: O = P V -----------------------------------
    f32x4 o[4][2];
    #pragma unroll
    for (int mo = 0; mo < 4; ++mo)
        #pragma unroll
        for (int dt = 0; dt < 2; ++dt)
            o[mo][dt] = (f32x4){0.f, 0.f, 0.f, 0.f};

    #pragma unroll
    for (int kt = 0; kt < 2; ++kt) {
        short8 bvv[2];
        #pragma unroll
        for (int dt = 0; dt < 2; ++dt)
            bvv[dt] = *(const short8*)(const void*)
                      &vtb[swz64(dt * 16 + l16, kt * 32 + quad * 8)];
        #pragma unroll
        for (int mo = 0; mo < 4; ++mo)
            #pragma unroll
            for (int dt = 0; dt < 2; ++dt)
                o[mo][dt] = __builtin_amdgcn_mfma_f32_16x16x32_bf16(
                                ap[mo][kt], bvv[dt], o[mo][dt], 0, 0, 0);
    }

    __syncthreads();   // all waves past phase-2 x reads; region[0..] becomes O_all
    #pragma unroll
    for (int dt = 0; dt < 2; ++dt)
        #pragma unroll
        for (int mt = 0; mt < 4; ++mt)
            #pragma unroll
            for (int r = 0; r < 4; ++r)
                region[(mt * 16 + quad * 4 + r) * 200 + h * 32 + dt * 16 + l16]
                    = f2bf(o[mt][dt][r]);
    __syncthreads();

    // ---------------- phase 6: projection GEMM + bias + fp32 store -------
    f32x4 po[2][4];
    #pragma unroll
    for (int nt = 0; nt < 2; ++nt)
        #pragma unroll
        for (int mt = 0; mt < 4; ++mt)
            po[nt][mt] = (f32x4){0.f, 0.f, 0.f, 0.f};

    #pragma unroll
    for (int kt = 0; kt < 6; ++kt) {
        short8 ao[4];
        #pragma unroll
        for (int mt = 0; mt < 4; ++mt)
            ao[mt] = *(const short8*)(const void*)
                     &region[(mt * 16 + l16) * 200 + kt * 32 + quad * 8];
        #pragma unroll
        for (int nt = 0; nt < 2; ++nt) {
            int col = h * 32 + nt * 16 + l16;
            short8 bw = *(const short8*)(const void*)
                        &wpj[(size_t)(kt * 192 + col) * 32 + quad * 8];
            #pragma unroll
            for (int mt = 0; mt < 4; ++mt)
                po[nt][mt] = __builtin_amdgcn_mfma_f32_16x16x32_bf16(
                                 ao[mt], bw, po[nt][mt], 0, 0, 0);
        }
    }

    #pragma unroll
    for (int nt = 0; nt < 2; ++nt) {
        int col = h * 32 + nt * 16 + l16;
        float bv = bproj[col];
        #pragma unroll
        for (int mt = 0; mt < 4; ++mt)
            #pragma unroll
            for (int r = 0; r < 4; ++r) {
                int row = mt * 16 + quad * 4 + r;
                if (row < 49)
                    out[(size_t)b * 9408 + row * 192 + col] = po[nt][mt][r] + bv;
            }
    }
}

extern "C" void kernel_launch(void* const* d_in, const int* in_sizes, int n_in,
                              void* d_out, int out_size, void* d_ws, size_t ws_size,
                              hipStream_t stream) {
    const float* x      = (const float*)d_in[0];
    const int*   mask   = (const int*)d_in[1];
    const float* w_qkv  = (const float*)d_in[2];
    const float* b_qkv  = (const float*)d_in[3];
    const float* w_proj = (const float*)d_in[4];
    const float* b_proj = (const float*)d_in[5];
    float*       out    = (float*)d_out;

    unsigned short* wq_pack = (unsigned short*)d_ws;          // 110592 elems
    unsigned short* wp_pack = wq_pack + 110592;               //  36864 elems

    repack_kernel<<<(110592 + 36864 + 255) / 256, 256, 0, stream>>>(
        w_qkv, w_proj, wq_pack, wp_pack);
    win_attn_kernel<<<8192, 384, 0, stream>>>(x, mask, b_qkv, b_proj,
                                              wq_pack, wp_pack, out);
}